// Round 5
// baseline (4540.207 us; speedup 1.0000x reference)
//
#include <hip/hip_runtime.h>
#include <hip/hip_bf16.h>
#include <cstdint>
#include <cstddef>

#define B_    32
#define S_    512
#define IN_   256
#define HID_  512
#define NGATE 1024
#define OUT_  256
#define NWGD  16         // worker WGs per direction (each owns 32 r/u/cand cols)

typedef float f32x4 __attribute__((ext_vector_type(4)));
typedef short bf16x8 __attribute__((ext_vector_type(8)));
typedef unsigned long long ull;

__device__ inline unsigned short f2bf(float f) {
  return __builtin_bit_cast(unsigned short, __float2bfloat16(f));
}
__device__ inline float bf2f(unsigned short u) {
  union { float f; unsigned int i; } v; v.i = ((unsigned int)u) << 16; return v.f;
}

// ---- cache-controlled stores -------------------------------------------
// slow mode (any placement): sc0 sc1 write-through to IF$ (device coherent
// point).  Baseline-proven.
// fast mode (all 16 WGs of a direction runtime-verified on ONE XCD; R2/R3/
// R4-proven correct): sc0 only — store lands in the XCD's shared L2 and
// consumer loads (first-touch-after-flag / post-buffer_inv) read it there.
__device__ inline void store_short_cc(unsigned short* p, unsigned short val, bool fast) {
  unsigned v = val;
  if (fast) asm volatile("global_store_short %0, %1, off sc0"     :: "v"(p), "v"(v) : "memory");
  else      asm volatile("global_store_short %0, %1, off sc0 sc1" :: "v"(p), "v"(v) : "memory");
}
__device__ inline void store_dword_wt(unsigned* p, unsigned val) {
  asm volatile("global_store_dword %0, %1, off sc0 sc1" :: "v"(p), "v"(val) : "memory");
}
__device__ inline void store_dword_l2(unsigned* p, unsigned val) {
  asm volatile("global_store_dword %0, %1, off sc0" :: "v"(p), "v"(val) : "memory");
}

// ---------------------------------------------------------------- prep ----
__global__ void prep_kernel(const float* __restrict__ x,
                            const float* __restrict__ fcw,
                            unsigned short* __restrict__ Xbf,
                            unsigned short* __restrict__ HFW,
                            unsigned short* __restrict__ HBW,
                            float* __restrict__ pool,
                            unsigned* __restrict__ sync,
                            unsigned short* __restrict__ fcwf)
{
  const int nthreads = gridDim.x * blockDim.x;
  const int gtid = blockIdx.x * blockDim.x + threadIdx.x;

  // x [B,S,IN] -> Xbf [S][B][IN] bf16
  for (int i = gtid; i < S_*B_*IN_; i += nthreads) {
    int c = i & (IN_-1);
    int rem = i >> 8;
    int b = rem & (B_-1);
    int s = rem >> 5;
    Xbf[((size_t)s*B_ + b)*IN_ + c] = f2bf(x[((size_t)b*S_ + s)*IN_ + c]);
  }
  // HFW[0] = 0 (h_{-1}), HBW[S-1] = 0 (hb_S)
  for (int i = gtid; i < B_*HID_; i += nthreads) {
    HFW[i] = 0;
    HBW[(size_t)(S_-1)*B_*HID_ + i] = 0;
  }
  for (int i = gtid; i < B_*HID_; i += nthreads) pool[i] = 0.f;
  for (int i = gtid; i < 16384;   i += nthreads) sync[i] = 0u;
  // fc_w [1280][512] -> fragment order [kc=40][nt=32][lane=64][8]
  for (int i = gtid; i < 40*32*64*8; i += nthreads) {
    int j     = i & 7;
    int lane_ = (i >> 3) & 63;
    int nt    = (i >> 9) & 31;
    int kc    = i >> 14;
    int k = kc*32 + (lane_ >> 4)*8 + j;
    int n = nt*16 + (lane_ & 15);
    fcwf[i] = f2bf(fcw[(size_t)k*HID_ + n]);
  }
}

// ------------------------------------------------------------- pregemm ----
// GX[dir][t*32+b][1024] = x_{t,b} @ Wg[0:256,:] + bg   (bf16)
// GC[dir][t*32+b][512]  = x_{t,b} @ Wc[0:256,:] + bc   (bf16)
__global__ __launch_bounds__(256, 1)
void pregemm_kernel(const unsigned short* __restrict__ Xbf,
                    const float* __restrict__ Wg_fw, const float* __restrict__ bg_fw,
                    const float* __restrict__ Wc_fw, const float* __restrict__ bc_fw,
                    const float* __restrict__ Wg_bw, const float* __restrict__ bg_bw,
                    const float* __restrict__ Wc_bw, const float* __restrict__ bc_bw,
                    unsigned short* __restrict__ GX, unsigned short* __restrict__ GC)
{
  __shared__ unsigned short bsm[4*8*64*8];   // 32KB [nt4][kk8][lane][8]
  const int id  = blockIdx.x;                // 0..12287
  const int dir = id >= 6144;
  const int r0  = id - dir*6144;
  const int mtile = r0 / 24;
  const int sec   = r0 % 24;
  const bool isG  = sec < 16;
  const float* W    = dir ? (isG ? Wg_bw : Wc_bw) : (isG ? Wg_fw : Wc_fw);
  const float* bias = dir ? (isG ? bg_bw : bc_bw) : (isG ? bg_fw : bc_fw);
  const int N     = isG ? NGATE : HID_;
  const int nbase = (isG ? sec : sec - 16) * 64;
  unsigned short* out = isG ? (GX + (size_t)dir*16384*NGATE)
                            : (GC + (size_t)dir*16384*HID_);
  const int m0 = mtile * 64;
  const int tid = threadIdx.x, wave = tid >> 6, lane = tid & 63;
  const int quad = lane >> 4, l16 = lane & 15;

  for (int idx = tid; idx < 4*8*64; idx += 256) {
    int lane_ = idx & 63, kk = (idx >> 6) & 7, nt = idx >> 9;
    int n  = nbase + nt*16 + (lane_ & 15);
    int kb = kk*32 + (lane_ >> 4)*8;
    #pragma unroll
    for (int j = 0; j < 8; ++j)
      bsm[((nt*8 + kk)*64 + lane_)*8 + j] = f2bf(W[(size_t)(kb + j)*N + n]);
  }
  __syncthreads();

  f32x4 acc[4];
  #pragma unroll
  for (int nt = 0; nt < 4; ++nt) acc[nt] = (f32x4){0.f,0.f,0.f,0.f};
  #pragma unroll
  for (int kk = 0; kk < 8; ++kk) {
    bf16x8 af = *(const bf16x8*)(Xbf + (size_t)(m0 + wave*16 + l16)*IN_ + quad*8 + kk*32);
    #pragma unroll
    for (int nt = 0; nt < 4; ++nt) {
      bf16x8 bv = *(const bf16x8*)(&bsm[((nt*8 + kk)*64 + lane)*8]);
      acc[nt] = __builtin_amdgcn_mfma_f32_16x16x32_bf16(af, bv, acc[nt], 0, 0, 0);
    }
  }
  #pragma unroll
  for (int nt = 0; nt < 4; ++nt)
    #pragma unroll
    for (int r = 0; r < 4; ++r) {
      int row = m0 + wave*16 + quad*4 + r;
      int col = nbase + nt*16 + l16;
      out[(size_t)row*N + col] = f2bf(acc[nt][r] + bias[col]);
    }
}

// ----------------------------------------------------------- barrier ----
// PER-WAVE sub-flags: 64 flags per {dir, phase}, one per producing wave
// (16 WGs x 4 waves), each on its own 64B line.  Producer wave drains its
// OWN stores (s_waitcnt vmcnt(0)) then lane0 posts — no __syncthreads in
// the step loop at all.  Consumer: lane l polls flag l (one wave-wide
// load per iteration covers all 64 producers).
// slow channel (baseline-proven): post sc0 sc1 (IF$), poll agent-scope.
// fast channel (same-XCD verified): post sc0 (shared L2); poll =
// buffer_inv sc0 (local CU-L1 invalidate) + plain load -> L2 hit.  Slow
// flag ALWAYS posted; fast waiters check it every 8th spin — any fast-
// channel surprise degrades to slow latency, never a hang (R2 lesson).
__device__ inline void wait64(const unsigned* basef, const unsigned* bases,
                              unsigned target, bool fast, int lane) {
  if (fast) {
    const volatile unsigned* pf = basef + lane*16;
    const unsigned* ps = bases + lane*16;
    int it = 0;
    for (;;) {
      asm volatile("buffer_inv sc0" ::: "memory");
      unsigned v = *pf;
      if (!__any((int)(v < target))) return;
      if ((++it & 7) == 0) {
        unsigned w = __hip_atomic_load(ps, __ATOMIC_RELAXED, __HIP_MEMORY_SCOPE_AGENT);
        if (!__any((int)(w < target))) return;
      }
      __builtin_amdgcn_s_sleep(1);
    }
  } else {
    const unsigned* ps = bases + lane*16;
    for (;;) {
      unsigned v = __hip_atomic_load(ps, __ATOMIC_RELAXED, __HIP_MEMORY_SCOPE_AGENT);
      if (!__any((int)(v < target))) return;
      __builtin_amdgcn_s_sleep(1);
    }
  }
}

__device__ inline void drain_post(unsigned* pf, unsigned* ps, unsigned val,
                                  bool fast, int lane) {
  asm volatile("s_waitcnt vmcnt(0)" ::: "memory");   // own stores at L2/IF$
  if (lane == 0) {
    if (fast) store_dword_l2(pf, val);
    store_dword_wt(ps, val);
  }
}

// --------------------------------------------------------------- gru ----
// Spray launch: 128 blocks; active iff (blockIdx & 7) < 2 -> dir d pinned
// to XCD d (R2/R3-verified; FETCH 374MB->85MB).  Runtime XCC_ID verdict;
// on mismatch -> baseline device-scope protocol (correct on any mapping).
//
// De-barriered step loop (this round's change):
//  waves 4-7: r-gate tiles (amt=q&1, ro=q>>1); store rh; post fA[g*4+q].
//  waves 0-3: u-gate tiles with amt=w&1, uo=w>>1 == their phase-B tile
//             (bmt,bnt) -> u STAYS IN REGISTERS (no LDS, no barrier);
//             then wait all 64 fA sub-flags, do cand GEMM + h-update,
//             post fB[g*4+w].
//  Step top: all waves wait all 64 fB sub-flags (h_t complete).
//  No __syncthreads in the loop; per-wave vmcnt drain + lane0 post.
__global__ __launch_bounds__(512, 1)
void gru_kernel(const float* __restrict__ Wg_fw, const float* __restrict__ Wc_fw,
                const float* __restrict__ Wg_bw, const float* __restrict__ Wc_bw,
                const unsigned short* __restrict__ GX, const unsigned short* __restrict__ GC,
                unsigned short* __restrict__ HFW, unsigned short* __restrict__ HBW,
                unsigned short* __restrict__ RH, unsigned* __restrict__ sync)
{
  __shared__ __align__(16) unsigned short wg_lds[4][16][512];  // 64KB gate B-frags
  __shared__ __align__(16) unsigned short wc_lds[2][16][512];  // 32KB cand B-frags

  const int slot = blockIdx.x & 7;
  if (slot >= 2) return;                    // inactive spray block
  const int dir = slot;
  const int g   = blockIdx.x >> 3;          // 0..15
  const int tid = threadIdx.x;
  const int wave = tid >> 6, lane = tid & 63;
  const int quad = lane >> 4, l16 = lane & 15;

  const float* Wg = dir ? Wg_bw : Wg_fw;
  const float* Wc = dir ? Wc_bw : Wc_fw;
  unsigned short* H = dir ? HBW : HFW;                 // [S][B][HID]
  unsigned short* RHd = RH + (size_t)dir*S_*B_*HID_;   // [S][B][HID]
  const unsigned short* GXd = GX + (size_t)dir*16384*NGATE;
  const unsigned short* GCd = GC + (size_t)dir*16384*HID_;
  // flag layout (dwords, zeroed by prep): per dir 4096-dword block
  unsigned* fAf = sync + dir*4096;            // fast A sub-flags (64 x 16dw)
  unsigned* fBf = sync + dir*4096 + 1024;     // fast B sub-flags
  unsigned* fAs = sync + dir*4096 + 2048;     // slow A sub-flags
  unsigned* fBs = sync + dir*4096 + 3072;     // slow B sub-flags

  // ---- publish own XCD id (device scope; area zeroed by prep) ----
  {
    // s_getreg_b32 simm16 = size-1[15:11] | offset[10:6] | id[5:0]; XCC_ID=20
    unsigned xcc = __builtin_amdgcn_s_getreg((31 << 11) | (0 << 6) | 20);
    if (tid == 0) store_dword_wt(sync + 8192 + dir*64 + g*4, 0x100u | (xcc & 0xFu));
  }

  // ---- stage weight h-rows (256..767) into LDS as B-fragments ----
  for (int idx = tid; idx < 4*16*64; idx += 512) {
    int lane_ = idx & 63, kk = (idx >> 6) & 15, nt = idx >> 10;
    int l16_ = lane_ & 15;
    int n = (nt < 2) ? (g*32 + nt*16 + l16_) : (512 + g*32 + (nt-2)*16 + l16_);
    int kb = IN_ + kk*32 + (lane_ >> 4)*8;
    #pragma unroll
    for (int j = 0; j < 8; ++j)
      wg_lds[nt][kk][lane_*8 + j] = f2bf(Wg[(size_t)(kb + j)*NGATE + n]);
  }
  for (int idx = tid; idx < 2*16*64; idx += 512) {
    int lane_ = idx & 63, kk = (idx >> 6) & 15, nt = idx >> 10;
    int n  = g*32 + nt*16 + (lane_ & 15);
    int kb = IN_ + kk*32 + (lane_ >> 4)*8;
    #pragma unroll
    for (int j = 0; j < 8; ++j)
      wc_lds[nt][kk][lane_*8 + j] = f2bf(Wc[(size_t)(kb + j)*HID_ + n]);
  }
  __syncthreads();

  // ---- gather all 16 XCD ids of this direction -> uniform verdict ----
  bool fast;
  {
    const unsigned* p = sync + 8192 + dir*64 + (tid & 15)*4;
    unsigned v;
    for (;;) {
      v = __hip_atomic_load(p, __ATOMIC_RELAXED, __HIP_MEMORY_SCOPE_AGENT);
      if (!__any((int)((v & 0x100u) == 0u))) break;
      __builtin_amdgcn_s_sleep(1);
    }
    unsigned v0 = __shfl(v, 0, 64);         // lane0 holds slot 0's id
    fast = (__all((int)(v == v0)) != 0);    // all 16 WGs on one XCD?
  }

  // tile assignment
  const int q   = wave & 3;                 // 0..3 within each half
  const int amt = q & 1;                    // row-block (both phases)
  const int nsl = q >> 1;                   // col-slice within 32-col block
  const int b0  = amt*16 + quad*4;          // 4 output rows
  const bool isR = wave >= 4;               // waves 4-7: r; waves 0-3: u+B
  const int colg = isR ? (g*32 + nsl*16 + l16)              // r-gate col
                       : (512 + g*32 + nsl*16 + l16);       // u-gate col
  const int colB = g*32 + nsl*16 + l16;     // cand/h col (waves 0-3)

  for (int si = 0; si < S_; ++si) {
    const int t  = dir ? (S_-1-si) : si;
    const int to = dir ? (t-1)     : (t+1);
    const unsigned short* Ht = H + (size_t)t*B_*HID_;

    // ---- prefetch h-independent operands BEFORE the flag wait ----
    unsigned short gx_s[4], gc_s[4];
    {
      const unsigned short* gx = GXd + (size_t)t*B_*NGATE;
      #pragma unroll
      for (int r = 0; r < 4; ++r) gx_s[r] = gx[(size_t)(b0 + r)*NGATE + colg];
      if (!isR) {
        #pragma unroll
        for (int r = 0; r < 4; ++r)
          gc_s[r] = GCd[((size_t)t*B_ + b0 + r)*HID_ + colB];
      }
    }

    wait64(fBf, fBs, (unsigned)si, fast, lane);   // h_prev (H[t]) complete

    if (isR) {
      // ======== waves 4-7: r = sigmoid(h@Wg_r + GX); rh -> RHd ========
      float hpA[4];
      #pragma unroll
      for (int r = 0; r < 4; ++r) hpA[r] = bf2f(Ht[(size_t)(b0 + r)*HID_ + colg]);
      const unsigned short* arow = Ht + (size_t)(amt*16 + l16)*HID_ + quad*8;
      f32x4 a0 = {0.f,0.f,0.f,0.f}, a1 = {0.f,0.f,0.f,0.f};
      #pragma unroll
      for (int kk = 0; kk < 16; ++kk) {
        bf16x8 af = *(const bf16x8*)(arow + kk*32);
        bf16x8 bv = *(const bf16x8*)(&wg_lds[nsl][kk][lane*8]);
        if (kk & 1) a1 = __builtin_amdgcn_mfma_f32_16x16x32_bf16(af, bv, a1, 0, 0, 0);
        else        a0 = __builtin_amdgcn_mfma_f32_16x16x32_bf16(af, bv, a0, 0, 0, 0);
      }
      f32x4 acc = a0 + a1;
      #pragma unroll
      for (int r = 0; r < 4; ++r) {
        float rv = 1.f / (1.f + __expf(-(acc[r] + bf2f(gx_s[r]))));
        store_short_cc(&RHd[(size_t)t*B_*HID_ + (size_t)(b0 + r)*HID_ + colg],
                       f2bf(rv * hpA[r]), fast);
      }
      drain_post(fAf + (g*4 + q)*16, fAs + (g*4 + q)*16, (unsigned)(si + 1),
                 fast, lane);
    } else {
      // ======== waves 0-3: u in regs; then cand GEMM + h update ========
      float hpB[4];
      #pragma unroll
      for (int r = 0; r < 4; ++r) hpB[r] = bf2f(Ht[(size_t)(b0 + r)*HID_ + colB]);
      const unsigned short* arow = Ht + (size_t)(amt*16 + l16)*HID_ + quad*8;
      f32x4 a0 = {0.f,0.f,0.f,0.f}, a1 = {0.f,0.f,0.f,0.f};
      #pragma unroll
      for (int kk = 0; kk < 16; ++kk) {
        bf16x8 af = *(const bf16x8*)(arow + kk*32);
        bf16x8 bv = *(const bf16x8*)(&wg_lds[2 + nsl][kk][lane*8]);
        if (kk & 1) a1 = __builtin_amdgcn_mfma_f32_16x16x32_bf16(af, bv, a1, 0, 0, 0);
        else        a0 = __builtin_amdgcn_mfma_f32_16x16x32_bf16(af, bv, a0, 0, 0, 0);
      }
      f32x4 acc = a0 + a1;
      float uv[4];
      #pragma unroll
      for (int r = 0; r < 4; ++r)
        uv[r] = 1.f / (1.f + __expf(-(acc[r] + bf2f(gx_s[r]))));

      wait64(fAf, fAs, (unsigned)(si + 1), fast, lane);  // rh complete

      const unsigned short* rrow = RHd + (size_t)t*B_*HID_
                                 + (size_t)(amt*16 + l16)*HID_ + quad*8;
      f32x4 c0 = {0.f,0.f,0.f,0.f}, c1 = {0.f,0.f,0.f,0.f};
      #pragma unroll
      for (int kk = 0; kk < 16; ++kk) {
        bf16x8 af = *(const bf16x8*)(rrow + kk*32);
        bf16x8 bv = *(const bf16x8*)(&wc_lds[nsl][kk][lane*8]);
        if (kk & 1) c1 = __builtin_amdgcn_mfma_f32_16x16x32_bf16(af, bv, c1, 0, 0, 0);
        else        c0 = __builtin_amdgcn_mfma_f32_16x16x32_bf16(af, bv, c0, 0, 0, 0);
      }
      f32x4 cacc = c0 + c1;
      if (to >= 0 && to < S_) {
        #pragma unroll
        for (int r = 0; r < 4; ++r) {
          float c  = tanhf(cacc[r] + bf2f(gc_s[r]));
          float hn = uv[r] * hpB[r] + (1.f - uv[r]) * c;
          store_short_cc(&H[((size_t)to*B_ + b0 + r)*HID_ + colB], f2bf(hn), fast);
        }
      }
      drain_post(fBf + (g*4 + q)*16, fBs + (g*4 + q)*16, (unsigned)(si + 1),
                 fast, lane);
    }
  }
}

// ---------------------------------------------------------------- fc ----
// last[b][t] = [HFW[t] | Xbf[t] | HBW[t]]; pool = max_t relu(last@fcw+fcb)
__global__ __launch_bounds__(512, 1)
void fc_kernel(const unsigned short* __restrict__ HFW, const unsigned short* __restrict__ HBW,
               const unsigned short* __restrict__ Xbf,
               const unsigned short* __restrict__ fcwf, const float* __restrict__ fcb,
               float* __restrict__ pool)
{
  __shared__ unsigned short bsm[32*512];   // 32KB weight chunk (frag order)
  __shared__ float red[8*512];             // 16KB cross-wave max reduce
  const int wg = blockIdx.x;               // 128 WGs: b = wg/4, t-quarter = wg%4
  const int b  = wg >> 2;
  const int tid = threadIdx.x, wave = tid >> 6, lane = tid & 63;
  const int quad = lane >> 4, l16 = lane & 15;
  const int t = (wg & 3)*128 + wave*16 + l16;  // A-operand row = t

  f32x4 acc[32];
  #pragma unroll
  for (int nt = 0; nt < 32; ++nt) acc[nt] = (f32x4){0.f,0.f,0.f,0.f};

  for (int kc = 0; kc < 40; ++kc) {
    __syncthreads();
    const uint4* src = (const uint4*)(fcwf + (size_t)kc*32*512);
    uint4* dst = (uint4*)bsm;
    #pragma unroll
    for (int r = 0; r < 4; ++r) dst[tid + r*512] = src[tid + r*512];
    __syncthreads();

    const unsigned short* ap;
    if (kc < 16)      ap = HFW + ((size_t)t*B_ + b)*HID_ + kc*32 + quad*8;        // c_left
    else if (kc < 24) ap = Xbf + ((size_t)t*B_ + b)*IN_ + (kc - 16)*32 + quad*8;  // x
    else              ap = HBW + ((size_t)t*B_ + b)*HID_ + (kc - 24)*32 + quad*8; // c_right
    const bf16x8 af = *(const bf16x8*)ap;
    #pragma unroll
    for (int nt = 0; nt < 32; ++nt) {
      bf16x8 bfv = *(const bf16x8*)(&bsm[(nt*64 + lane)*8]);
      acc[nt] = __builtin_amdgcn_mfma_f32_16x16x32_bf16(af, bfv, acc[nt], 0, 0, 0);
    }
  }
  #pragma unroll
  for (int nt = 0; nt < 32; ++nt) {
    float m = fmaxf(fmaxf(acc[nt][0], acc[nt][1]), fmaxf(acc[nt][2], acc[nt][3]));
    m = fmaxf(m, __shfl_xor(m, 16, 64));
    m = fmaxf(m, __shfl_xor(m, 32, 64));
    if (quad == 0) red[wave*512 + nt*16 + l16] = m;
  }
  __syncthreads();
  {
    float m = red[tid];
    #pragma unroll
    for (int w = 1; w < 8; ++w) m = fmaxf(m, red[w*512 + tid]);
    m = fmaxf(m + fcb[tid], 0.f);
    atomicMax((int*)&pool[(size_t)b*HID_ + tid], __float_as_int(m));
  }
}

// --------------------------------------------------------------- mlp ----
__global__ void mlp_kernel(const float* __restrict__ pool, const float* __restrict__ w,
                           const float* __restrict__ bias, float* __restrict__ out)
{
  __shared__ float p[HID_];
  const int b = blockIdx.x, tid = threadIdx.x;  // 256 threads
  p[tid]       = pool[(size_t)b*HID_ + tid];
  p[tid + 256] = pool[(size_t)b*HID_ + 256 + tid];
  __syncthreads();
  float acc = bias[tid];
  for (int k = 0; k < HID_; ++k) acc += p[k] * w[(size_t)k*OUT_ + tid];
  out[(size_t)b*OUT_ + tid] = acc;
}

// ------------------------------------------------------------ launch ----
extern "C" void kernel_launch(void* const* d_in, const int* in_sizes, int n_in,
                              void* d_out, int out_size, void* d_ws, size_t ws_size,
                              hipStream_t stream)
{
  const float* x    = (const float*)d_in[0];
  const float* fwWg = (const float*)d_in[1];
  const float* fwbg = (const float*)d_in[2];
  const float* fwWc = (const float*)d_in[3];
  const float* fwbc = (const float*)d_in[4];
  const float* bwWg = (const float*)d_in[5];
  const float* bwbg = (const float*)d_in[6];
  const float* bwWc = (const float*)d_in[7];
  const float* bwbc = (const float*)d_in[8];
  const float* fcw  = (const float*)d_in[9];
  const float* fcb  = (const float*)d_in[10];
  const float* mlpw = (const float*)d_in[11];
  const float* mlpb = (const float*)d_in[12];
  float* out = (float*)d_out;

  char* p = (char*)d_ws;
  auto take = [&](size_t bytes) { char* r = p; p += (bytes + 255) & ~size_t(255); return r; };
  unsigned short* Xbf  = (unsigned short*)take((size_t)S_*B_*IN_*2);          // 8MB
  unsigned short* HFW  = (unsigned short*)take((size_t)S_*B_*HID_*2);         // 16.8MB
  unsigned short* HBW  = (unsigned short*)take((size_t)S_*B_*HID_*2);         // 16.8MB
  unsigned short* GX   = (unsigned short*)take((size_t)2*S_*B_*NGATE*2);      // 67MB
  unsigned short* GC   = (unsigned short*)take((size_t)2*S_*B_*HID_*2);       // 33.6MB
  unsigned short* RH   = (unsigned short*)take((size_t)2*S_*B_*HID_*2);       // 33.6MB
  unsigned short* fcwf = (unsigned short*)take((size_t)40*32*64*8*2);         // 1.25MB
  float*          pool = (float*)take((size_t)B_*HID_*4);
  unsigned*       sync = (unsigned*)take(65536);

  prep_kernel<<<2048, 256, 0, stream>>>(x, fcw, Xbf, HFW, HBW, pool, sync, fcwf);
  pregemm_kernel<<<12288, 256, 0, stream>>>(Xbf, fwWg, fwbg, fwWc, fwbc,
                                            bwWg, bwbg, bwWc, bwbc, GX, GC);
  // spray launch: 128 blocks, active = blockIdx%8 in {0,1}  -> one XCD/dir
  gru_kernel<<<128, 512, 0, stream>>>(fwWg, fwWc, bwWg, bwWc,
                                      GX, GC, HFW, HBW, RH, sync);
  fc_kernel<<<128, 512, 0, stream>>>(HFW, HBW, Xbf, fcwf, fcb, pool);
  mlp_kernel<<<32, 256, 0, stream>>>(pool, mlpw, mlpb, out);
}